// Round 6
// baseline (49.064 us; speedup 1.0000x reference)
//
#include <hip/hip_runtime.h>

// Problem constants (match reference)
#define NB  2      // batches
#define NP  8192   // points per batch
#define IMH 256
#define IMW 256
#define NBKT 1024  // x-buckets per batch

constexpr float R2F = 0.01f;      // RADIUS^2 (np weak promotion -> f32)
constexpr float BK_SCALE = 64.f;  // bucket width 1/64 over x in [-8, 8)
constexpr float BK_OFF   = 8.f;
#define BK_PAD 7                  // ceil(0.1001 * 64) = 7  (conservative cull)

__device__ __forceinline__ int bucket_of(float x) {
    int b = (int)floorf((x + BK_OFF) * BK_SCALE);
    return min(max(b, 0), NBKT - 1);
}

// ---------------------------------------------------------------------------
// Kernel A: zero d_out (98304 f4), img_w (32768 f4), ghist (512 i4) in one
// dispatch (replaces two memset nodes + ghist clear).
// ---------------------------------------------------------------------------
__global__ __launch_bounds__(256) void init_kernel(
    float4* __restrict__ out4, float4* __restrict__ imgw4, int4* __restrict__ gh4)
{
    const int t = blockIdx.x * 256 + threadIdx.x;
    const float4 z4 = make_float4(0.f, 0.f, 0.f, 0.f);
    if (t < 98304) out4[t] = z4;
    if (t < 32768) imgw4[t] = z4;
    if (t < 512)   gh4[t]   = make_int4(0, 0, 0, 0);
}

// ---------------------------------------------------------------------------
// Kernel B: histogram — one global atomic per point (avg 8 hits/bucket,
// L2-resident counters). 64 blocks.
// ---------------------------------------------------------------------------
__global__ __launch_bounds__(256) void hist_kernel(
    const float* __restrict__ pts, int* __restrict__ ghist)
{
    const int tid = blockIdx.x * 256 + threadIdx.x;    // 0 .. NB*NP-1
    const int b = tid >> 13;
    const float x = pts[(size_t)tid * 3];
    atomicAdd(&ghist[b * NBKT + bucket_of(x)], 1);
}

// ---------------------------------------------------------------------------
// Kernel C: per-batch exclusive scan of 1024 bucket counts (Hillis-Steele,
// ping-pong LDS); writes offsets[b][0..NBKT] and seeds gcur.
// ---------------------------------------------------------------------------
__global__ __launch_bounds__(1024) void scan_kernel(
    const int* __restrict__ ghist, int* __restrict__ offsets, int* __restrict__ gcur)
{
    __shared__ int A[NBKT], Bs[NBKT];
    const int b = blockIdx.x, tid = threadIdx.x;
    A[tid] = ghist[b * NBKT + tid];
    __syncthreads();
    int* src = A; int* dst = Bs;
    for (int off = 1; off < NBKT; off <<= 1) {
        int v = src[tid];
        if (tid >= off) v += src[tid - off];
        dst[tid] = v;
        __syncthreads();
        int* tmp = src; src = dst; dst = tmp;
    }
    const int start = tid ? src[tid - 1] : 0;
    offsets[b * (NBKT + 1) + tid] = start;
    gcur[b * NBKT + tid] = start;
    if (tid == 0) offsets[b * (NBKT + 1) + NBKT] = NP;
}

// ---------------------------------------------------------------------------
// Kernel D: scatter into sorted order; slot via global atomic (bucket-internal
// order nondeterministic, but the pair SET tested downstream is order-
// invariant; f32 sum-order noise ~1e-7 << 2e-2). sq uses the numpy recipe
// (rounded muls, sequential adds, no FMA). 64 blocks.
// ---------------------------------------------------------------------------
__global__ __launch_bounds__(256) void scatter_kernel(
    const float* __restrict__ pts, int* __restrict__ gcur,
    float4* __restrict__ sorted, int* __restrict__ sidx)
{
    const int tid = blockIdx.x * 256 + threadIdx.x;    // 0 .. NB*NP-1
    const int b = tid >> 13, i = tid & (NP - 1);
    const float x = pts[(size_t)tid * 3 + 0];
    const float y = pts[(size_t)tid * 3 + 1];
    const float z = pts[(size_t)tid * 3 + 2];
    const int slot = atomicAdd(&gcur[b * NBKT + bucket_of(x)], 1);
    const float sq = __fadd_rn(__fadd_rn(__fmul_rn(x, x), __fmul_rn(y, y)),
                               __fmul_rn(z, z));
    sorted[(size_t)b * NP + slot] = make_float4(x, y, z, sq);
    sidx  [(size_t)b * NP + slot] = i;
}

// ---------------------------------------------------------------------------
// Kernel 1: windowed gaussian density over x-sorted points (unchanged / R5
// passing). numpy f32 semantics: dot = fma(z*z', fma(y*y', rn(x*x'))),
// d2 = (sq_i+sq_j) - 2*dot, include iff max(d2,0) <= 0.01f,
// w = expf((d2c/0.01f) * -0.25f). Cull: |dx| <= 0.1001 -> buckets +-7.
// ---------------------------------------------------------------------------
__global__ __launch_bounds__(256) void density_kernel(
    const float4* __restrict__ sorted, const int* __restrict__ sidx,
    const int* __restrict__ offsets, float* __restrict__ density)
{
    const int wave = threadIdx.x >> 6, lane = threadIdx.x & 63;
    const int w  = blockIdx.x * 4 + wave;       // 0 .. NB*NP/8-1
    const int s0 = w * 8;
    const int b  = s0 >> 13;
    const int sb = s0 & (NP - 1);
    const float4* __restrict__ sp = sorted + (size_t)b * NP;

    float xi[8], yi[8], zi[8], sqi[8], sum[8];
    #pragma unroll
    for (int t = 0; t < 8; ++t) {
        const float4 p = sp[sb + t];
        xi[t] = p.x; yi[t] = p.y; zi[t] = p.z; sqi[t] = p.w;
        sum[t] = 0.f;
    }
    const int blo = max(bucket_of(xi[0]) - BK_PAD, 0);
    const int bhi = min(bucket_of(xi[7]) + BK_PAD + 1, NBKT);
    const int jlo = offsets[b * (NBKT + 1) + blo];
    const int jhi = offsets[b * (NBKT + 1) + bhi];

    for (int jj = jlo + lane; jj < jhi; jj += 64) {
        const float4 pj = sp[jj];
        #pragma unroll
        for (int t = 0; t < 8; ++t) {
            const float dot = __fmaf_rn(zi[t], pj.z,
                              __fmaf_rn(yi[t], pj.y,
                              __fmul_rn(xi[t], pj.x)));
            const float d2 = __fsub_rn(__fadd_rn(sqi[t], pj.w),
                                       __fadd_rn(dot, dot));
            const float d2c = fmaxf(d2, 0.f);
            if (jj != sb + t && d2c <= R2F)
                sum[t] += expf(__fmul_rn(__fdiv_rn(d2c, R2F), -0.25f));
        }
    }
    #pragma unroll
    for (int t = 0; t < 8; ++t) {
        float s = sum[t];
        #pragma unroll
        for (int off2 = 32; off2; off2 >>= 1) s += __shfl_down(s, off2, 64);
        if (lane == 0) density[(size_t)b * NP + sidx[(size_t)b * NP + sb + t]] = s;
    }
}

// ---------------------------------------------------------------------------
// Kernel 2: elliptical gaussian splat (unchanged / passing).
// ---------------------------------------------------------------------------
__global__ __launch_bounds__(256) void splat_kernel(
    const float* __restrict__ proj, const float* __restrict__ ell,
    const float* __restrict__ cols, const float* __restrict__ density,
    float* __restrict__ img_c, float* __restrict__ img_w)
{
    const int wave = threadIdx.x >> 6;
    const int lane = threadIdx.x & 63;
    const int pid  = blockIdx.x * 4 + wave;
    const float dens = density[pid];
    if (dens == 0.f) return;                      // exact-zero contribution
    const int b = pid >> 13;
    const float x = proj[pid * 2 + 0], y = proj[pid * 2 + 1];
    const float a  = ell[pid * 3 + 0], bb = ell[pid * 3 + 1], c = ell[pid * 3 + 2];
    const float cr = cols[pid * 3 + 0], cg = cols[pid * 3 + 1], cb = cols[pid * 3 + 2];

    const float den = __fsub_rn(__fmul_rn(__fmul_rn(4.f, a), bb),
                                __fmul_rn(c, c));
    const float xE = fminf(__fsqrt_rn(__fdiv_rn(__fmul_rn(4.f, bb), den)), 15.f);
    const float yE = fminf(__fsqrt_rn(__fdiv_rn(__fmul_rn(4.f, a),  den)), 15.f);
    const float xEp1 = __fadd_rn(xE, 1.f);
    const float yEp1 = __fadd_rn(yE, 1.f);
    const float x0 = floorf(x), y0 = floorf(y);

    for (int idx = lane; idx < 81; idx += 64) {
        const float ox = (float)(idx / 9) - 4.f;   // meshgrid 'ij': ox slow axis
        const float oy = (float)(idx % 9) - 4.f;
        const float px = __fadd_rn(x0, ox);        // exact (small integers)
        const float py = __fadd_rn(y0, oy);
        if (px < 0.f || px >= 256.f || py < 0.f || py >= 256.f) continue;
        const float dx = __fsub_rn(px, x);
        const float dy = __fsub_rn(py, y);
        if (fabsf(dx) > xEp1 || fabsf(dy) > yEp1) continue;
        const float Q = __fadd_rn(__fadd_rn(__fmul_rn(__fmul_rn(a, dx), dx),
                                            __fmul_rn(__fmul_rn(bb, dy), dy)),
                                  __fmul_rn(__fmul_rn(c, dx), dy));
        if (!(Q <= 1.0f)) continue;
        const float w = __fmul_rn(expf(__fmul_rn(-0.5f, Q)), dens);
        const int pxi = (int)px, pyi = (int)py;
        const int flat = ((b << 8) + pyi) * IMW + pxi;
        atomicAdd(&img_c[flat * 3 + 0], __fmul_rn(w, cr));
        atomicAdd(&img_c[flat * 3 + 1], __fmul_rn(w, cg));
        atomicAdd(&img_c[flat * 3 + 2], __fmul_rn(w, cb));
        atomicAdd(&img_w[flat],         w);
    }
}

// ---------------------------------------------------------------------------
// Kernel 3: per-pixel normalize: out = img_c / (img_w + eps)
// ---------------------------------------------------------------------------
__global__ void norm_kernel(float* __restrict__ out, const float* __restrict__ img_w)
{
    const int p = blockIdx.x * 256 + threadIdx.x;
    if (p < NB * IMH * IMW) {
        const float d = __fadd_rn(img_w[p], 1e-8f);
        out[3 * p + 0] = __fdiv_rn(out[3 * p + 0], d);
        out[3 * p + 1] = __fdiv_rn(out[3 * p + 1], d);
        out[3 * p + 2] = __fdiv_rn(out[3 * p + 2], d);
    }
}

extern "C" void kernel_launch(void* const* d_in, const int* in_sizes, int n_in,
                              void* d_out, int out_size, void* d_ws, size_t ws_size,
                              hipStream_t stream)
{
    const float* points = (const float*)d_in[0];   // [NB,NP,3]
    const float* proj   = (const float*)d_in[1];   // [NB,NP,2]
    const float* ell    = (const float*)d_in[2];   // [NB,NP,3]
    const float* cols   = (const float*)d_in[3];   // [NB,NP,3]
    float* out = (float*)d_out;                    // [NB,IMH,IMW,3] = img_c accumulator

    // workspace layout (float4 first to keep 16B alignment)
    float4* sorted  = (float4*)d_ws;                           // NB*NP float4
    float*  img_w   = (float*)(sorted + (size_t)NB * NP);      // NB*IMH*IMW
    float*  density = img_w + (size_t)NB * IMH * IMW;          // NB*NP
    int*    sidx    = (int*)(density + (size_t)NB * NP);       // NB*NP
    int*    offsets = sidx + (size_t)NB * NP;                  // NB*(NBKT+1)
    int*    ghist   = offsets + NB * (NBKT + 1) + 3;           // NB*NBKT (16B-aligned: +3 pads 2050->2053? keep simple below)
    // re-derive 16B-aligned ghist/gcur:
    ghist = (int*)((((size_t)(offsets + NB * (NBKT + 1))) + 15) & ~(size_t)15);
    int*    gcur    = ghist + NB * NBKT;                       // NB*NBKT

    init_kernel   <<<384, 256, 0, stream>>>((float4*)out, (float4*)img_w, (int4*)ghist);
    hist_kernel   <<<NB * NP / 256, 256, 0, stream>>>(points, ghist);
    scan_kernel   <<<NB, 1024, 0, stream>>>(ghist, offsets, gcur);
    scatter_kernel<<<NB * NP / 256, 256, 0, stream>>>(points, gcur, sorted, sidx);
    density_kernel<<<NB * NP / 32, 256, 0, stream>>>(sorted, sidx, offsets, density);
    splat_kernel  <<<NB * NP / 4,  256, 0, stream>>>(proj, ell, cols, density, out, img_w);
    norm_kernel   <<<(NB * IMH * IMW + 255) / 256, 256, 0, stream>>>(out, img_w);
}

// Round 7
// 41.251 us; speedup vs baseline: 1.1894x; 1.1894x over previous
//
#include <hip/hip_runtime.h>

// Problem constants (match reference)
#define NB  2      // batches
#define NP  8192   // points per batch
#define IMH 256
#define IMW 256
#define NBKT 1024  // x-buckets per batch

constexpr float R2F = 0.01f;      // RADIUS^2 (np weak promotion -> f32)
constexpr float BK_SCALE = 64.f;  // bucket width 1/64 over x in [-8, 8)
constexpr float BK_OFF   = 8.f;
#define BK_PAD 7                  // ceil(0.1001 * 64) = 7  (conservative cull)

__device__ __forceinline__ int bucket_of(float x) {
    int b = (int)floorf((x + BK_OFF) * BK_SCALE);
    return min(max(b, 0), NBKT - 1);
}

// ---------------------------------------------------------------------------
// Kernel A: zero d_out (98304 f4) and img_w (32768 f4). Nothing else needs
// zeroing: binsort's counters live in its own LDS.
// ---------------------------------------------------------------------------
__global__ __launch_bounds__(256) void init_kernel(
    float4* __restrict__ out4, float4* __restrict__ imgw4)
{
    const int t = blockIdx.x * 256 + threadIdx.x;
    const float4 z4 = make_float4(0.f, 0.f, 0.f, 0.f);
    if (t < 98304) out4[t] = z4;
    if (t < 32768) imgw4[t] = z4;
}

// ---------------------------------------------------------------------------
// Kernel B: fused per-batch counting sort by x-bucket (R5, proven).
// One block (1024 threads) per batch: LDS histogram -> Hillis-Steele scan ->
// scatter {x,y,z,sq} float4 + original index. sq uses the numpy recipe
// (rounded muls, sequential adds, no FMA). Bucket-internal order from LDS
// atomics is nondeterministic, but the pair SET tested downstream is
// order-invariant; f32 sum-order noise ~1e-7 << 2e-2 threshold.
// ---------------------------------------------------------------------------
__global__ __launch_bounds__(1024) void binsort_kernel(
    const float* __restrict__ pts, float4* __restrict__ sorted,
    int* __restrict__ sidx, int* __restrict__ offsets)
{
    __shared__ int cntA[NBKT], cntB[NBKT], cur[NBKT];
    const int b   = blockIdx.x;
    const int tid = threadIdx.x;
    const float* __restrict__ base = pts + (size_t)b * NP * 3;

    cntA[tid] = 0;
    __syncthreads();

    float xs[8], ys[8], zs[8]; int bks[8];
    #pragma unroll
    for (int k = 0; k < 8; ++k) {
        const int i = k * 1024 + tid;
        xs[k] = base[i * 3 + 0];
        ys[k] = base[i * 3 + 1];
        zs[k] = base[i * 3 + 2];
        bks[k] = bucket_of(xs[k]);
        atomicAdd(&cntA[bks[k]], 1);
    }
    __syncthreads();

    // inclusive scan over 1024 counts (ping-pong, 10 steps)
    int* src = cntA; int* dst = cntB;
    for (int off = 1; off < NBKT; off <<= 1) {
        int v = src[tid];
        if (tid >= off) v += src[tid - off];
        dst[tid] = v;
        __syncthreads();
        int* tmp = src; src = dst; dst = tmp;
    }
    const int start = (tid == 0) ? 0 : src[tid - 1];
    offsets[b * (NBKT + 1) + tid] = start;
    if (tid == 0) offsets[b * (NBKT + 1) + NBKT] = NP;
    cur[tid] = start;
    __syncthreads();

    #pragma unroll
    for (int k = 0; k < 8; ++k) {
        const int i = k * 1024 + tid;
        const int slot = atomicAdd(&cur[bks[k]], 1);
        const float sq = __fadd_rn(__fadd_rn(__fmul_rn(xs[k], xs[k]),
                                             __fmul_rn(ys[k], ys[k])),
                                   __fmul_rn(zs[k], zs[k]));
        sorted[(size_t)b * NP + slot] = make_float4(xs[k], ys[k], zs[k], sq);
        sidx  [(size_t)b * NP + slot] = i;
    }
}

// ---------------------------------------------------------------------------
// Kernel C: FUSED windowed density + elliptical splat.
// Per wave: 8 consecutive sorted slots. Phase 1 (R5 density, proven):
//   dot = fma(z*z', fma(y*y', rn(x*x')))   (einsum -ffp-contract=fast chain)
//   d2  = (sq_i+sq_j) - 2*dot; include iff max(d2,0) <= 0.01f
//   w   = expf((d2c/0.01f) * -0.25f); cull via buckets [bk-7, bk+7].
// Phase 2 (R5 splat, proven): reduce+broadcast density, then the SAME wave
// splats that point's 81-px window with scatter atomics. Density array and
// its global round-trip are eliminated.
// ---------------------------------------------------------------------------
__global__ __launch_bounds__(256) void densplat_kernel(
    const float4* __restrict__ sorted, const int* __restrict__ sidx,
    const int* __restrict__ offsets,
    const float* __restrict__ proj, const float* __restrict__ ell,
    const float* __restrict__ cols,
    float* __restrict__ img_c, float* __restrict__ img_w)
{
    const int wave = threadIdx.x >> 6, lane = threadIdx.x & 63;
    const int w  = blockIdx.x * 4 + wave;       // 0 .. NB*NP/8-1
    const int s0 = w * 8;
    const int b  = s0 >> 13;
    const int sb = s0 & (NP - 1);
    const float4* __restrict__ sp = sorted + (size_t)b * NP;

    float xi[8], yi[8], zi[8], sqi[8], sum[8];
    #pragma unroll
    for (int t = 0; t < 8; ++t) {
        const float4 p = sp[sb + t];
        xi[t] = p.x; yi[t] = p.y; zi[t] = p.z; sqi[t] = p.w;
        sum[t] = 0.f;
    }
    const int blo = max(bucket_of(xi[0]) - BK_PAD, 0);
    const int bhi = min(bucket_of(xi[7]) + BK_PAD + 1, NBKT);
    const int jlo = offsets[b * (NBKT + 1) + blo];
    const int jhi = offsets[b * (NBKT + 1) + bhi];

    for (int jj = jlo + lane; jj < jhi; jj += 64) {
        const float4 pj = sp[jj];
        #pragma unroll
        for (int t = 0; t < 8; ++t) {
            const float dot = __fmaf_rn(zi[t], pj.z,
                              __fmaf_rn(yi[t], pj.y,
                              __fmul_rn(xi[t], pj.x)));
            const float d2 = __fsub_rn(__fadd_rn(sqi[t], pj.w),
                                       __fadd_rn(dot, dot));
            const float d2c = fmaxf(d2, 0.f);
            if (jj != sb + t && d2c <= R2F)
                sum[t] += expf(__fmul_rn(__fdiv_rn(d2c, R2F), -0.25f));
        }
    }

    // Phase 2: per-point reduce, broadcast, splat (R5 splat math verbatim).
    #pragma unroll
    for (int t = 0; t < 8; ++t) {
        float s = sum[t];
        #pragma unroll
        for (int off2 = 32; off2; off2 >>= 1) s += __shfl_down(s, off2, 64);
        const float dens = __shfl(s, 0, 64);      // broadcast total to all lanes
        if (dens == 0.f) continue;                // exact-zero contribution

        const size_t gp = (size_t)b * NP + sidx[(size_t)b * NP + sb + t];
        const float x = proj[gp * 2 + 0], y = proj[gp * 2 + 1];
        const float a  = ell[gp * 3 + 0], bb = ell[gp * 3 + 1], c = ell[gp * 3 + 2];
        const float cr = cols[gp * 3 + 0], cg = cols[gp * 3 + 1], cb = cols[gp * 3 + 2];

        const float den = __fsub_rn(__fmul_rn(__fmul_rn(4.f, a), bb),
                                    __fmul_rn(c, c));
        const float xE = fminf(__fsqrt_rn(__fdiv_rn(__fmul_rn(4.f, bb), den)), 15.f);
        const float yE = fminf(__fsqrt_rn(__fdiv_rn(__fmul_rn(4.f, a),  den)), 15.f);
        const float xEp1 = __fadd_rn(xE, 1.f);
        const float yEp1 = __fadd_rn(yE, 1.f);
        const float x0 = floorf(x), y0 = floorf(y);

        for (int idx = lane; idx < 81; idx += 64) {
            const float ox = (float)(idx / 9) - 4.f;   // meshgrid 'ij': ox slow axis
            const float oy = (float)(idx % 9) - 4.f;
            const float px = __fadd_rn(x0, ox);        // exact (small integers)
            const float py = __fadd_rn(y0, oy);
            if (px < 0.f || px >= 256.f || py < 0.f || py >= 256.f) continue;
            const float dx = __fsub_rn(px, x);
            const float dy = __fsub_rn(py, y);
            if (fabsf(dx) > xEp1 || fabsf(dy) > yEp1) continue;
            const float Q = __fadd_rn(__fadd_rn(__fmul_rn(__fmul_rn(a, dx), dx),
                                                __fmul_rn(__fmul_rn(bb, dy), dy)),
                                      __fmul_rn(__fmul_rn(c, dx), dy));
            if (!(Q <= 1.0f)) continue;
            const float wgt = __fmul_rn(expf(__fmul_rn(-0.5f, Q)), dens);
            const int pxi = (int)px, pyi = (int)py;
            const int flat = ((b << 8) + pyi) * IMW + pxi;
            atomicAdd(&img_c[flat * 3 + 0], __fmul_rn(wgt, cr));
            atomicAdd(&img_c[flat * 3 + 1], __fmul_rn(wgt, cg));
            atomicAdd(&img_c[flat * 3 + 2], __fmul_rn(wgt, cb));
            atomicAdd(&img_w[flat],         wgt);
        }
    }
}

// ---------------------------------------------------------------------------
// Kernel D: per-pixel normalize: out = img_c / (img_w + eps)
// ---------------------------------------------------------------------------
__global__ void norm_kernel(float* __restrict__ out, const float* __restrict__ img_w)
{
    const int p = blockIdx.x * 256 + threadIdx.x;
    if (p < NB * IMH * IMW) {
        const float d = __fadd_rn(img_w[p], 1e-8f);
        out[3 * p + 0] = __fdiv_rn(out[3 * p + 0], d);
        out[3 * p + 1] = __fdiv_rn(out[3 * p + 1], d);
        out[3 * p + 2] = __fdiv_rn(out[3 * p + 2], d);
    }
}

extern "C" void kernel_launch(void* const* d_in, const int* in_sizes, int n_in,
                              void* d_out, int out_size, void* d_ws, size_t ws_size,
                              hipStream_t stream)
{
    const float* points = (const float*)d_in[0];   // [NB,NP,3]
    const float* proj   = (const float*)d_in[1];   // [NB,NP,2]
    const float* ell    = (const float*)d_in[2];   // [NB,NP,3]
    const float* cols   = (const float*)d_in[3];   // [NB,NP,3]
    float* out = (float*)d_out;                    // [NB,IMH,IMW,3] = img_c accumulator

    // workspace layout (float4 first to keep 16B alignment)
    float4* sorted  = (float4*)d_ws;                           // NB*NP float4
    float*  img_w   = (float*)(sorted + (size_t)NB * NP);      // NB*IMH*IMW
    int*    sidx    = (int*)(img_w + (size_t)NB * IMH * IMW);  // NB*NP
    int*    offsets = sidx + (size_t)NB * NP;                  // NB*(NBKT+1)

    init_kernel    <<<384, 256, 0, stream>>>((float4*)out, (float4*)img_w);
    binsort_kernel <<<NB, 1024, 0, stream>>>(points, sorted, sidx, offsets);
    densplat_kernel<<<NB * NP / 32, 256, 0, stream>>>(sorted, sidx, offsets,
                                                      proj, ell, cols, out, img_w);
    norm_kernel    <<<(NB * IMH * IMW + 255) / 256, 256, 0, stream>>>(out, img_w);
}